// Round 4
// baseline (210.400 us; speedup 1.0000x reference)
//
#include <hip/hip_runtime.h>

typedef unsigned short ushort_t;
typedef unsigned int   uint_t;

typedef __attribute__((ext_vector_type(8))) short  short8;   // 8 bf16 in 4 VGPRs
typedef __attribute__((ext_vector_type(4))) short  short4v;  // 4 bf16 (b64)
typedef __attribute__((ext_vector_type(4))) float  float4v;  // MFMA 16x16 acc

#define BB    8
#define CC    256
#define HH    64
#define WW2   64
#define NPIX  4096   // H*W
#define MPOS  1024   // (H/2)*(W/2)
#define ICH   64

__device__ __forceinline__ float bf2f(ushort_t u) {
  return __uint_as_float(((uint_t)u) << 16);
}
__device__ __forceinline__ ushort_t f2bf(float f) {
  uint_t i = __float_as_uint(f);
  uint_t r = (i + 0x7FFFu + ((i >> 16) & 1u)) >> 16;  // RNE
  return (ushort_t)r;
}
__device__ __forceinline__ ushort_t f2bf_rna(float f) {   // cheap round-half-away
  return (ushort_t)((__float_as_uint(f) + 0x8000u) >> 16);
}
__device__ __forceinline__ uint_t pack2(float a, float b) {
  return (uint_t)f2bf(a) | ((uint_t)f2bf(b) << 16);
}

// ---------------------------------------------------------------------------
// K0: xpose + prep.
// blocks [0,2048): x[b][c][p] fp32 -> xT[b][p][c] bf16 via LDS 64x64 tile.
// blocks [2048,2305): weight prep (wAll [192][256], Wbf [256][64], biasAll).
// ---------------------------------------------------------------------------
__global__ __launch_bounds__(256) void xpose_prep_kernel(
    const float* __restrict__ x,
    const float* __restrict__ theta_w, const float* __restrict__ phi_w,
    const float* __restrict__ g_w, const float* __restrict__ W_w,
    const float* __restrict__ theta_b, const float* __restrict__ phi_b,
    const float* __restrict__ g_b,
    ushort_t* __restrict__ xT, ushort_t* __restrict__ wAll,
    ushort_t* __restrict__ Wbf, float* __restrict__ biasAll) {
  int bid = blockIdx.x;
  int tid = threadIdx.x;
  if (bid < 2048) {
    __shared__ __align__(16) ushort_t T[64 * 72];
    int b = bid >> 8, rest = bid & 255;
    int ct = rest >> 6, pt = rest & 63;      // 64-channel group, 64-pixel group
    int w = tid >> 6, pl = tid & 63;
    const float* src = x + ((size_t)(b * CC + ct * 64)) * NPIX + pt * 64;
#pragma unroll
    for (int i = 0; i < 16; ++i) {
      int cl = i * 4 + w;
      T[pl * 72 + cl] = f2bf(src[(size_t)cl * NPIX + pl]);
    }
    __syncthreads();
#pragma unroll
    for (int j = 0; j < 2; ++j) {
      int flat = tid * 2 + j;                // 0..511
      int p = flat >> 3, seg = flat & 7;
      uint4 v = *(const uint4*)&T[p * 72 + seg * 8];
      *(uint4*)&xT[((size_t)(b * NPIX + pt * 64 + p)) * CC + ct * 64 + seg * 8] = v;
    }
  } else {
    int i = (bid - 2048) * 256 + tid;
    if (i < 16384)        wAll[i] = f2bf(theta_w[i]);
    else if (i < 32768)   wAll[i] = f2bf(phi_w[i - 16384]);
    else if (i < 49152)   wAll[i] = f2bf(g_w[i - 32768]);
    else if (i < 65536)   Wbf[i - 49152] = f2bf(W_w[i - 49152]);
    else if (i < 65600)   biasAll[i - 65536] = theta_b[i - 65536];
    else if (i < 65664)   biasAll[i - 65536] = phi_b[i - 65600];
    else if (i < 65728)   biasAll[i - 65536] = g_b[i - 65664];
  }
}

// ---------------------------------------------------------------------------
// K1: q/k/v conv GEMM + 2x2 maxpool. Pure MFMA, NO LDS, NO barriers.
// Grid 1024 = 8 b x 128 tiles (2 rows x 16 cols = 32 pixels).
// M=192 (theta|phi|g) x N=32 x K=256. Wave w: o-rows [48w,48w+48).
// A-frags from wAll (L2-hot), B-frags direct from xT (8 contiguous channels
// per lane = native B-layout). Pooling in-register (s-pair + lane^1).
// ---------------------------------------------------------------------------
__global__ __launch_bounds__(256, 4) void qkv_kernel(
    const ushort_t* __restrict__ xT, const ushort_t* __restrict__ wAll,
    const float* __restrict__ biasAll,
    ushort_t* __restrict__ qbuf, ushort_t* __restrict__ kTbuf,
    ushort_t* __restrict__ vTbuf) {
  int tid = threadIdx.x;
  int wave = tid >> 6, lane = tid & 63;
  int quad = lane >> 4, col = lane & 15;
  int b = blockIdx.x >> 7, tile = blockIdx.x & 127;
  int r2 = tile >> 2, co = tile & 3;         // row-pair, 16-col group

  const ushort_t* brow0 = xT + ((size_t)(b * NPIX + (2 * r2 + 0) * WW2 + co * 16 + col)) * CC;
  const ushort_t* brow1 = xT + ((size_t)(b * NPIX + (2 * r2 + 1) * WW2 + co * 16 + col)) * CC;
  const ushort_t* wbase = wAll + (size_t)(wave * 48 + col) * CC;

  float4v acc[3][2];
#pragma unroll
  for (int ot = 0; ot < 3; ++ot) {
    int ob = wave * 48 + ot * 16 + quad * 4;
    float4v bv;
#pragma unroll
    for (int r = 0; r < 4; ++r) bv[r] = biasAll[ob + r];
    acc[ot][0] = bv;
    acc[ot][1] = bv;
  }

#pragma unroll
  for (int kc = 0; kc < 4; ++kc) {
#pragma unroll
    for (int ksl = 0; ksl < 2; ++ksl) {
      int koff = kc * 64 + ksl * 32 + quad * 8;
      short8 aw[3];
#pragma unroll
      for (int ot = 0; ot < 3; ++ot)
        aw[ot] = *(const short8*)&wbase[(size_t)(ot * 16) * CC + koff];
      short8 b0 = *(const short8*)&brow0[koff];
      short8 b1 = *(const short8*)&brow1[koff];
#pragma unroll
      for (int ot = 0; ot < 3; ++ot) {
        acc[ot][0] = __builtin_amdgcn_mfma_f32_16x16x32_bf16(aw[ot], b0, acc[ot][0], 0, 0, 0);
        acc[ot][1] = __builtin_amdgcn_mfma_f32_16x16x32_bf16(aw[ot], b1, acc[ot][1], 0, 0, 0);
      }
    }
  }

  // epilogue: lane value = (o = ob+quad*4+r, pixel row 2r2+s, col co*16+col)
#pragma unroll
  for (int ot = 0; ot < 3; ++ot) {
    int ob = wave * 48 + ot * 16;
    if (ob < 64) {  // theta -> qbuf[b][n][o]
#pragma unroll
      for (int s = 0; s < 2; ++s) {
        int n = (2 * r2 + s) * WW2 + co * 16 + col;
        uint2 u;
        u.x = pack2(acc[ot][s][0], acc[ot][s][1]);
        u.y = pack2(acc[ot][s][2], acc[ot][s][3]);
        *(uint2*)&qbuf[((size_t)(b * NPIX + n)) * ICH + ob + quad * 4] = u;
      }
    } else if (ob < 128) {  // phi -> pool -> kTbuf[b][m][ic]
      float4v pm;
#pragma unroll
      for (int r = 0; r < 4; ++r) {
        float v = fmaxf(acc[ot][0][r], acc[ot][1][r]);
        pm[r] = fmaxf(v, __shfl_xor(v, 1));
      }
      if ((lane & 1) == 0) {
        int m = r2 * 32 + co * 8 + (col >> 1);
        uint2 u;
        u.x = pack2(pm[0], pm[1]);
        u.y = pack2(pm[2], pm[3]);
        *(uint2*)&kTbuf[((size_t)(b * MPOS + m)) * ICH + (ob - 64) + quad * 4] = u;
      }
    } else {  // g -> pool -> vTbuf[b][ic][m]
      float4v pm;
#pragma unroll
      for (int r = 0; r < 4; ++r) {
        float v = fmaxf(acc[ot][0][r], acc[ot][1][r]);
        pm[r] = fmaxf(v, __shfl_xor(v, 1));
      }
      if ((lane & 1) == 0) {
        int m = r2 * 32 + co * 8 + (col >> 1);
#pragma unroll
        for (int r = 0; r < 4; ++r)
          vTbuf[((size_t)(b * ICH + (ob - 128) + quad * 4 + r)) * MPOS + m] = f2bf(pm[r]);
      }
    }
  }
}

// ---------------------------------------------------------------------------
// K2: attention, no-max softmax (scores bounded, exp safe; partials linear).
// Grid 1024 = 8 b x 128 q-tiles of 32. 4 waves: wq=wave&1 (16-q half),
// wk=wave>>1 (kt half: wk*8+i). Each iter stages BOTH kt tiles (i, 8+i),
// single-buffered with register prefetch. Final merge of wk partials via LDS.
// ---------------------------------------------------------------------------
__global__ __launch_bounds__(256, 3) void attn_kernel(
    const ushort_t* __restrict__ qbuf, const ushort_t* __restrict__ kTbuf,
    const ushort_t* __restrict__ vTbuf, ushort_t* __restrict__ attbuf) {
  __shared__ __align__(16) ushort_t Ks[2][64 * 64];
  __shared__ __align__(16) ushort_t Vs[2][64 * 64];
  __shared__ __align__(16) ushort_t Ps[64 * 68];
  int tid  = threadIdx.x;
  int wave = tid >> 6, lane = tid & 63;
  int quad = lane >> 4, col = lane & 15;
  int wq = wave & 1, wk = wave >> 1;
  int b = blockIdx.x >> 7, qt = blockIdx.x & 127;

  // Q A-fragments straight from global
  const ushort_t* qrow = qbuf + ((size_t)(b * NPIX + qt * 32 + wq * 16 + col)) * ICH;
  short8 aQ0 = *(const short8*)&qrow[quad * 8];
  short8 aQ1 = *(const short8*)&qrow[32 + quad * 8];

  // staging: per thread 4 K uint4 + 4 V uint4 (2 per tile)
  int krow0 = tid >> 3, kblk = tid & 7;
  int krow1 = krow0 + 32;
  int vic = tid >> 2, vseg = tid & 3;
  const uint4* kbase = (const uint4*)(kTbuf + ((size_t)(b * MPOS)) * ICH);
  const ushort_t* vbase = vTbuf + ((size_t)(b * ICH + vic)) * MPOS;

  uint4 pk[4], pv[4];
#define AT_LOAD(i)                                                          \
  {                                                                         \
    const uint4* k0p = kbase + (size_t)(i) * 512;                           \
    const uint4* k1p = kbase + (size_t)((i) + 8) * 512;                     \
    pk[0] = k0p[tid]; pk[1] = k0p[tid + 256];                               \
    pk[2] = k1p[tid]; pk[3] = k1p[tid + 256];                               \
    const uint4* v0p = (const uint4*)(vbase + (i) * 64);                    \
    const uint4* v1p = (const uint4*)(vbase + ((i) + 8) * 64);              \
    pv[0] = v0p[vseg]; pv[1] = v0p[vseg + 4];                               \
    pv[2] = v1p[vseg]; pv[3] = v1p[vseg + 4];                               \
  }
#define AT_WRITE()                                                          \
  {                                                                         \
    *(uint4*)&Ks[0][krow0 * 64 + ((kblk ^ (krow0 & 7)) * 8)] = pk[0];       \
    *(uint4*)&Ks[0][krow1 * 64 + ((kblk ^ (krow1 & 7)) * 8)] = pk[1];       \
    *(uint4*)&Ks[1][krow0 * 64 + ((kblk ^ (krow0 & 7)) * 8)] = pk[2];       \
    *(uint4*)&Ks[1][krow1 * 64 + ((kblk ^ (krow1 & 7)) * 8)] = pk[3];       \
    *(uint4*)&Vs[0][vic * 64 + ((vseg ^ (vic & 7)) * 8)] = pv[0];           \
    *(uint4*)&Vs[0][vic * 64 + (((vseg + 4) ^ (vic & 7)) * 8)] = pv[1];     \
    *(uint4*)&Vs[1][vic * 64 + ((vseg ^ (vic & 7)) * 8)] = pv[2];           \
    *(uint4*)&Vs[1][vic * 64 + (((vseg + 4) ^ (vic & 7)) * 8)] = pv[3];     \
  }

  AT_LOAD(0);
  AT_WRITE();
  __syncthreads();

  const float4v zero4 = {0.f, 0.f, 0.f, 0.f};
  float l_lane[4] = {0.f, 0.f, 0.f, 0.f};
  float4v o_acc[4];
#pragma unroll
  for (int t = 0; t < 4; ++t) o_acc[t] = zero4;

  for (int i = 0; i < 8; ++i) {
    if (i < 7) AT_LOAD(i + 1);

    // S = Q . K^T on this wave's tile (wk)
    float4v s_acc[4];
#pragma unroll
    for (int t = 0; t < 4; ++t) {
      float4v s = zero4;
      short8 bk0 = *(const short8*)&Ks[wk][(t * 16 + col) * 64 + ((quad ^ (col & 7)) * 8)];
      s = __builtin_amdgcn_mfma_f32_16x16x32_bf16(aQ0, bk0, s, 0, 0, 0);
      short8 bk1 = *(const short8*)&Ks[wk][(t * 16 + col) * 64 + (((4 + quad) ^ (col & 7)) * 8)];
      s = __builtin_amdgcn_mfma_f32_16x16x32_bf16(aQ1, bk1, s, 0, 0, 0);
      s_acc[t] = s;
    }

    // P = exp(S); per-lane l accumulation; wave-private Ps rows
#pragma unroll
    for (int r = 0; r < 4; ++r) {
      int prow = (wave * 16 + quad * 4 + r) * 68;
#pragma unroll
      for (int t = 0; t < 4; ++t) {
        float pv_ = __expf(s_acc[t][r]);
        l_lane[r] += pv_;
        Ps[prow + t * 16 + col] = f2bf_rna(pv_);
      }
    }

    // O += P . V
#pragma unroll
    for (int kk = 0; kk < 2; ++kk) {
      int pbase = (wave * 16 + col) * 68 + kk * 32 + quad * 8;
      short4v plo = *(const short4v*)&Ps[pbase];
      short4v phi = *(const short4v*)&Ps[pbase + 4];
      short8 ap = __builtin_shufflevector(plo, phi, 0, 1, 2, 3, 4, 5, 6, 7);
#pragma unroll
      for (int t = 0; t < 4; ++t) {
        short8 bv = *(const short8*)&Vs[wk][(t * 16 + col) * 64 + (((kk * 4 + quad) ^ (col & 7)) * 8)];
        o_acc[t] = __builtin_amdgcn_mfma_f32_16x16x32_bf16(ap, bv, o_acc[t], 0, 0, 0);
      }
    }

    if (i < 7) {
      __syncthreads();   // everyone done reading Ks/Vs
      AT_WRITE();
      __syncthreads();   // tiles i+1 / 9+i visible
    }
  }
#undef AT_LOAD
#undef AT_WRITE

  // merge wk partials (linear: o and l just add), then normalize + store
  __syncthreads();
  float* S = (float*)Ks;  // 16KB scratch, done with K tiles
  if (wk == 1) {
    float* dst = S + (size_t)(wq * 64 + lane) * 20;
#pragma unroll
    for (int t = 0; t < 4; ++t)
#pragma unroll
      for (int r = 0; r < 4; ++r) dst[t * 4 + r] = o_acc[t][r];
#pragma unroll
    for (int r = 0; r < 4; ++r) dst[16 + r] = l_lane[r];
  }
  __syncthreads();
  if (wk == 0) {
    const float* srcp = S + (size_t)(wq * 64 + lane) * 20;
#pragma unroll
    for (int t = 0; t < 4; ++t)
#pragma unroll
      for (int r = 0; r < 4; ++r) o_acc[t][r] += srcp[t * 4 + r];
#pragma unroll
    for (int r = 0; r < 4; ++r) {
      float l = l_lane[r] + srcp[16 + r];
      l += __shfl_xor(l, 1);
      l += __shfl_xor(l, 2);
      l += __shfl_xor(l, 4);
      l += __shfl_xor(l, 8);
      float inv = 1.0f / l;
      size_t row = ((size_t)(b * NPIX + qt * 32 + wq * 16 + quad * 4 + r)) * ICH;
#pragma unroll
      for (int t = 0; t < 4; ++t)
        attbuf[row + t * 16 + col] = f2bf(o_acc[t][r] * inv);
    }
  }
}

// ---------------------------------------------------------------------------
// K3: out[b][o][p] = attended[p][:] . Wbf[o][:] + W_b[o] + x[b][o][p], MFMA.
// Grid 1024 = 8 b x 128 pixel-tiles of 32. Wave: 64 o x 32 p. No LDS.
// ---------------------------------------------------------------------------
__global__ __launch_bounds__(256, 4) void outconv_kernel(
    const ushort_t* __restrict__ attbuf, const float* __restrict__ x,
    const ushort_t* __restrict__ Wbf, const float* __restrict__ W_b,
    float* __restrict__ out) {
  int tid = threadIdx.x;
  int wave = tid >> 6, lane = tid & 63;
  int quad = lane >> 4, col = lane & 15;
  int b = blockIdx.x >> 7, pt = blockIdx.x & 127;

  float4v acc[4][2];  // [os][ps]
#pragma unroll
  for (int os = 0; os < 4; ++os) {
    float bv = W_b[wave * 64 + os * 16 + col];
    float4v bvec = {bv, bv, bv, bv};
    acc[os][0] = bvec;
    acc[os][1] = bvec;
  }

  short8 af[2][2];  // [ks][ps]
#pragma unroll
  for (int ps = 0; ps < 2; ++ps)
#pragma unroll
    for (int ks = 0; ks < 2; ++ks)
      af[ks][ps] = *(const short8*)&attbuf[((size_t)(b * NPIX + pt * 32 + ps * 16 + col)) * ICH +
                                           ks * 32 + quad * 8];

#pragma unroll
  for (int os = 0; os < 4; ++os) {
#pragma unroll
    for (int ks = 0; ks < 2; ++ks) {
      short8 wf = *(const short8*)&Wbf[(size_t)(wave * 64 + os * 16 + col) * ICH +
                                       ks * 32 + quad * 8];
      acc[os][0] = __builtin_amdgcn_mfma_f32_16x16x32_bf16(af[ks][0], wf, acc[os][0], 0, 0, 0);
      acc[os][1] = __builtin_amdgcn_mfma_f32_16x16x32_bf16(af[ks][1], wf, acc[os][1], 0, 0, 0);
    }
  }

#pragma unroll
  for (int os = 0; os < 4; ++os) {
#pragma unroll
    for (int ps = 0; ps < 2; ++ps) {
      int o = wave * 64 + os * 16 + col;
      int p = pt * 32 + ps * 16 + quad * 4;
      size_t idx = ((size_t)(b * CC + o)) * NPIX + p;
      float4 xv = *(const float4*)&x[idx];
      float4 ov;
      ov.x = acc[os][ps][0] + xv.x;
      ov.y = acc[os][ps][1] + xv.y;
      ov.z = acc[os][ps][2] + xv.z;
      ov.w = acc[os][ps][3] + xv.w;
      *(float4*)&out[idx] = ov;
    }
  }
}

// ---------------------------------------------------------------------------
extern "C" void kernel_launch(void* const* d_in, const int* in_sizes, int n_in,
                              void* d_out, int out_size, void* d_ws, size_t ws_size,
                              hipStream_t stream) {
  const float* x       = (const float*)d_in[0];
  const float* g_w     = (const float*)d_in[1];
  const float* g_b     = (const float*)d_in[2];
  const float* theta_w = (const float*)d_in[3];
  const float* theta_b = (const float*)d_in[4];
  const float* phi_w   = (const float*)d_in[5];
  const float* phi_b   = (const float*)d_in[6];
  const float* W_w     = (const float*)d_in[7];
  const float* W_b     = (const float*)d_in[8];
  (void)in_sizes; (void)n_in; (void)out_size; (void)ws_size;

  char* ws = (char*)d_ws;
  ushort_t* wAll    = (ushort_t*)(ws + 0);         // 96KB bf16 [192][256]
  ushort_t* Wbf     = (ushort_t*)(ws + 98304);     // 32KB bf16 [256][64]
  float*    biasAll = (float*)(ws + 131072);       // 768B
  ushort_t* xT      = (ushort_t*)(ws + 262144);    // 16.78MB bf16 [8][4096][256]
  ushort_t* attbuf  = (ushort_t*)(ws + 262144);    // alias xT (dead after qkv)
  ushort_t* qbuf    = (ushort_t*)(ws + 17039360);  // 4MB bf16 [8][4096][64]
  ushort_t* kTbuf   = (ushort_t*)(ws + 21233664);  // 1MB bf16 [8][1024][64]
  ushort_t* vTbuf   = (ushort_t*)(ws + 22282240);  // 1MB bf16 [8][64][1024]
  float* out = (float*)d_out;

  xpose_prep_kernel<<<2305, 256, 0, stream>>>(x, theta_w, phi_w, g_w, W_w,
                                              theta_b, phi_b, g_b,
                                              xT, wAll, Wbf, biasAll);
  qkv_kernel<<<1024, 256, 0, stream>>>(xT, wAll, biasAll, qbuf, kTbuf, vTbuf);
  attn_kernel<<<1024, 256, 0, stream>>>(qbuf, kTbuf, vTbuf, attbuf);
  outconv_kernel<<<1024, 256, 0, stream>>>(attbuf, x, Wbf, W_b, out);
}

// Round 5
// 139.020 us; speedup vs baseline: 1.5135x; 1.5135x over previous
//
#include <hip/hip_runtime.h>

typedef unsigned short ushort_t;
typedef unsigned int   uint_t;

typedef __attribute__((ext_vector_type(8))) short  short8;   // 8 bf16 in 4 VGPRs
typedef __attribute__((ext_vector_type(4))) short  short4v;  // 4 bf16 (b64)
typedef __attribute__((ext_vector_type(4))) float  float4v;  // MFMA 16x16 acc

#define BB    8
#define CC    256
#define HH    64
#define WW2   64
#define NPIX  4096   // H*W
#define MPOS  1024   // (H/2)*(W/2)
#define ICH   64

__device__ __forceinline__ float bf2f(ushort_t u) {
  return __uint_as_float(((uint_t)u) << 16);
}
__device__ __forceinline__ ushort_t f2bf(float f) {
  uint_t i = __float_as_uint(f);
  uint_t r = (i + 0x7FFFu + ((i >> 16) & 1u)) >> 16;  // RNE
  return (ushort_t)r;
}
__device__ __forceinline__ ushort_t f2bf_rna(float f) {   // cheap round-half-away
  return (ushort_t)((__float_as_uint(f) + 0x8000u) >> 16);
}
__device__ __forceinline__ uint_t pack2(float a, float b) {
  return (uint_t)f2bf(a) | ((uint_t)f2bf(b) << 16);
}

// ---------------------------------------------------------------------------
// K0: xpose + prep.
// blocks [0,2048): x[b][c][p] fp32 -> xT[b][p][c] bf16 via LDS 64x64 tile.
// blocks [2048,2305): weight prep into coalesced-fragment layouts:
//   wA2 [32 kblk][192 o][8 k]  (A-op frags: 16 consecutive uint4 per quad)
//   Wbf2 [8 kblk][256 o][8 k]  (B-op frags for outconv, same property)
//   biasAll [192] f32
// ---------------------------------------------------------------------------
__global__ __launch_bounds__(256) void xpose_prep_kernel(
    const float* __restrict__ x,
    const float* __restrict__ theta_w, const float* __restrict__ phi_w,
    const float* __restrict__ g_w, const float* __restrict__ W_w,
    const float* __restrict__ theta_b, const float* __restrict__ phi_b,
    const float* __restrict__ g_b,
    ushort_t* __restrict__ xT, ushort_t* __restrict__ wA2,
    ushort_t* __restrict__ Wbf2, float* __restrict__ biasAll) {
  int bid = blockIdx.x;
  int tid = threadIdx.x;
  if (bid < 2048) {
    __shared__ __align__(16) ushort_t T[64 * 72];
    int b = bid >> 8, rest = bid & 255;
    int ct = rest >> 6, pt = rest & 63;      // 64-channel group, 64-pixel group
    int w = tid >> 6, pl = tid & 63;
    const float* src = x + ((size_t)(b * CC + ct * 64)) * NPIX + pt * 64;
#pragma unroll
    for (int i = 0; i < 16; ++i) {
      int cl = i * 4 + w;
      T[pl * 72 + cl] = f2bf(src[(size_t)cl * NPIX + pl]);
    }
    __syncthreads();
#pragma unroll
    for (int j = 0; j < 2; ++j) {
      int flat = tid * 2 + j;                // 0..511
      int p = flat >> 3, seg = flat & 7;
      uint4 v = *(const uint4*)&T[p * 72 + seg * 8];
      *(uint4*)&xT[((size_t)(b * NPIX + pt * 64 + p)) * CC + ct * 64 + seg * 8] = v;
    }
  } else {
    int i = (bid - 2048) * 256 + tid;
    if (i < 49152) {         // theta|phi|g -> wA2
      float v = (i < 16384) ? theta_w[i]
              : (i < 32768) ? phi_w[i - 16384]
                            : g_w[i - 32768];
      int o = i >> 8, c = i & 255;
      wA2[(c >> 3) * 1536 + o * 8 + (c & 7)] = f2bf(v);
    } else if (i < 65536) {  // W_w -> Wbf2
      int j = i - 49152;
      int o = j >> 6, ic = j & 63;
      Wbf2[(ic >> 3) * 2048 + o * 8 + (ic & 7)] = f2bf(W_w[j]);
    } else if (i < 65600)    biasAll[i - 65536] = theta_b[i - 65536];
    else if (i < 65664)      biasAll[i - 65536] = phi_b[i - 65600];
    else if (i < 65728)      biasAll[i - 65536] = g_b[i - 65664];
  }
}

// ---------------------------------------------------------------------------
// K1: q/k/v conv GEMM + 2x2 maxpool. M=192 x N=64 x K=256 per block.
// Grid 512 = 8 b x 32 row-pairs x 2 col-halves. Tile pixels: rows {2j,2j+1}
// x cols [32h,32h+32) -> two contiguous 16KB xT chunks staged to LDS with
// XOR-swizzled b128 writes (conflict-free), full K resident, ONE barrier.
// A-frags from wA2 (coalesced). Wave w: o-rows [48w,48w+48), 96 MFMA.
// Pooling in-register: row partner s+2, col partner lane^1.
// ---------------------------------------------------------------------------
__global__ __launch_bounds__(256, 4) void qkv_kernel(
    const ushort_t* __restrict__ xT, const ushort_t* __restrict__ wA2,
    const float* __restrict__ biasAll,
    ushort_t* __restrict__ qbuf, ushort_t* __restrict__ kTbuf,
    ushort_t* __restrict__ vTbuf) {
  __shared__ __align__(16) ushort_t Bsu[64 * 256];
  uint4* Bs16 = (uint4*)Bsu;
  int tid = threadIdx.x;
  int wave = tid >> 6, lane = tid & 63;
  int quad = lane >> 4, col = lane & 15;
  int b = blockIdx.x >> 6, t = blockIdx.x & 63;
  int rj = t >> 1, h = t & 1;

  const uint4* src0 = (const uint4*)(xT + ((size_t)(b * NPIX + (2 * rj + 0) * WW2 + h * 32)) * CC);
  const uint4* src1 = (const uint4*)(xT + ((size_t)(b * NPIX + (2 * rj + 1) * WW2 + h * 32)) * CC);

  // stage 32KB: 2048 uint4, thread handles 8 (fully coalesced reads)
#pragma unroll
  for (int it = 0; it < 8; ++it) {
    int g = it * 256 + tid;                 // 0..2047
    int chunk = g >> 10, off = g & 1023;    // 1024 uint4 per chunk
    int lp = chunk * 32 + (off >> 5), j = off & 31;
    uint4 v = (chunk == 0) ? src0[off] : src1[off];
    Bs16[lp * 32 + (j & ~7) + ((j & 7) ^ (lp & 7))] = v;
  }
  __syncthreads();

  float4v acc[3][4];
#pragma unroll
  for (int ot = 0; ot < 3; ++ot) {
    int ob = wave * 48 + ot * 16 + quad * 4;
    float4v bv;
#pragma unroll
    for (int r = 0; r < 4; ++r) bv[r] = biasAll[ob + r];
#pragma unroll
    for (int s = 0; s < 4; ++s) acc[ot][s] = bv;
  }

  const uint4* wA16 = (const uint4*)wA2;
#pragma unroll
  for (int ks = 0; ks < 8; ++ks) {
    int kblk = ks * 4 + quad;               // 16B-block index in K (0..31)
    short8 aw[3];
#pragma unroll
    for (int ot = 0; ot < 3; ++ot) {
      uint4 a = wA16[kblk * 192 + wave * 48 + ot * 16 + col];
      aw[ot] = *(const short8*)&a;
    }
#pragma unroll
    for (int s = 0; s < 4; ++s) {
      int lp = s * 16 + col;
      uint4 braw = Bs16[lp * 32 + (kblk & ~7) + ((kblk & 7) ^ (lp & 7))];
      short8 bx = *(const short8*)&braw;
#pragma unroll
      for (int ot = 0; ot < 3; ++ot)
        acc[ot][s] = __builtin_amdgcn_mfma_f32_16x16x32_bf16(aw[ot], bx, acc[ot][s], 0, 0, 0);
    }
  }

  // epilogue: lane value (o = ob+quad*4+r, lp = s*16+col)
  // s<2: image row 2rj, cols h*32+s*16+col ; s>=2: row 2rj+1.
#pragma unroll
  for (int ot = 0; ot < 3; ++ot) {
    int ob = wave * 48 + ot * 16;
    if (ob < 64) {  // theta -> qbuf[b][n][o]
#pragma unroll
      for (int s = 0; s < 4; ++s) {
        int n = (2 * rj + (s >> 1)) * WW2 + h * 32 + (s & 1) * 16 + col;
        uint2 u;
        u.x = pack2(acc[ot][s][0], acc[ot][s][1]);
        u.y = pack2(acc[ot][s][2], acc[ot][s][3]);
        *(uint2*)&qbuf[((size_t)(b * NPIX + n)) * ICH + ob + quad * 4] = u;
      }
    } else if (ob < 128) {  // phi -> pool -> kTbuf[b][m][ic]
#pragma unroll
      for (int s = 0; s < 2; ++s) {
        float4v pm;
#pragma unroll
        for (int r = 0; r < 4; ++r) {
          float v = fmaxf(acc[ot][s][r], acc[ot][s + 2][r]);
          pm[r] = fmaxf(v, __shfl_xor(v, 1));
        }
        if ((lane & 1) == 0) {
          int m = rj * 32 + h * 16 + s * 8 + (col >> 1);
          uint2 u;
          u.x = pack2(pm[0], pm[1]);
          u.y = pack2(pm[2], pm[3]);
          *(uint2*)&kTbuf[((size_t)(b * MPOS + m)) * ICH + (ob - 64) + quad * 4] = u;
        }
      }
    } else {  // g -> pool -> vTbuf[b][ic][m]
#pragma unroll
      for (int s = 0; s < 2; ++s) {
        float4v pm;
#pragma unroll
        for (int r = 0; r < 4; ++r) {
          float v = fmaxf(acc[ot][s][r], acc[ot][s + 2][r]);
          pm[r] = fmaxf(v, __shfl_xor(v, 1));
        }
        if ((lane & 1) == 0) {
          int m = rj * 32 + h * 16 + s * 8 + (col >> 1);
#pragma unroll
          for (int r = 0; r < 4; ++r)
            vTbuf[((size_t)(b * ICH + (ob - 128) + quad * 4 + r)) * MPOS + m] = f2bf(pm[r]);
        }
      }
    }
  }
}

// ---------------------------------------------------------------------------
// K2: attention — exact r3 structure (no-max softmax, XOR-swizzled K/V,
// double-buffered with register prefetch of only 4 uint4 across ONE barrier,
// one barrier per kt). Q fragments direct from global.
// ---------------------------------------------------------------------------
__global__ __launch_bounds__(256, 2) void attn_kernel(
    const ushort_t* __restrict__ qbuf, const ushort_t* __restrict__ kTbuf,
    const ushort_t* __restrict__ vTbuf, ushort_t* __restrict__ attbuf) {
  __shared__ __align__(16) ushort_t Ks[2][64 * 64];
  __shared__ __align__(16) ushort_t Vs[2][64 * 64];
  __shared__ __align__(16) ushort_t Ps[64 * 68];
  int tid  = threadIdx.x;
  int wave = tid >> 6, lane = tid & 63;
  int quad = lane >> 4, col = lane & 15;
  int b = blockIdx.x >> 6, qt = blockIdx.x & 63;

  // Q A-fragments straight from global (one-time)
  const ushort_t* qrow = qbuf + ((size_t)(b * NPIX + qt * 64 + wave * 16 + col)) * ICH;
  short8 aQ0 = *(const short8*)&qrow[quad * 8];
  short8 aQ1 = *(const short8*)&qrow[32 + quad * 8];

  int krow0 = tid >> 3,           kblk0 = tid & 7;
  int krow1 = (tid + 256) >> 3,   kblk1 = tid & 7;
  int vic = tid >> 2, vseg = tid & 3;

  const uint4* ksrc0 = (const uint4*)(kTbuf + ((size_t)(b * MPOS)) * ICH);
  const ushort_t* vbase = vTbuf + ((size_t)(b * ICH + vic)) * MPOS;

  {
    uint4 k0 = ksrc0[tid], k1 = ksrc0[tid + 256];
    const uint4* vsrc = (const uint4*)(vbase + vseg * 16);
    uint4 v0 = vsrc[0], v1 = vsrc[1];
    *(uint4*)&Ks[0][krow0 * 64 + ((kblk0 ^ (krow0 & 7)) * 8)] = k0;
    *(uint4*)&Ks[0][krow1 * 64 + ((kblk1 ^ (krow1 & 7)) * 8)] = k1;
    *(uint4*)&Vs[0][vic * 64 + (((vseg * 2 + 0) ^ (vic & 7)) * 8)] = v0;
    *(uint4*)&Vs[0][vic * 64 + (((vseg * 2 + 1) ^ (vic & 7)) * 8)] = v1;
  }
  __syncthreads();

  const float4v zero4 = {0.f, 0.f, 0.f, 0.f};
  float l_lane[4] = {0.f, 0.f, 0.f, 0.f};
  float4v o_acc[4];
#pragma unroll
  for (int t = 0; t < 4; ++t) o_acc[t] = zero4;

  for (int kt = 0; kt < 16; ++kt) {
    uint4 nk0, nk1, nv0, nv1;
    if (kt < 15) {
      const uint4* ksrc = (const uint4*)(kTbuf + ((size_t)(b * MPOS + (kt + 1) * 64)) * ICH);
      nk0 = ksrc[tid];
      nk1 = ksrc[tid + 256];
      const uint4* vsrc = (const uint4*)(vbase + (kt + 1) * 64 + vseg * 16);
      nv0 = vsrc[0];
      nv1 = vsrc[1];
    }
    int buf = kt & 1;

    // S = Q . K^T
    float4v s_acc[4];
#pragma unroll
    for (int t = 0; t < 4; ++t) {
      float4v s = zero4;
      short8 bk0 = *(const short8*)&Ks[buf][(t * 16 + col) * 64 + ((quad ^ (col & 7)) * 8)];
      s = __builtin_amdgcn_mfma_f32_16x16x32_bf16(aQ0, bk0, s, 0, 0, 0);
      short8 bk1 = *(const short8*)&Ks[buf][(t * 16 + col) * 64 + (((4 + quad) ^ (col & 7)) * 8)];
      s = __builtin_amdgcn_mfma_f32_16x16x32_bf16(aQ1, bk1, s, 0, 0, 0);
      s_acc[t] = s;
    }

    // P = exp(S); per-lane l accumulation; wave-private Ps rows
#pragma unroll
    for (int r = 0; r < 4; ++r) {
      int prow = (wave * 16 + quad * 4 + r) * 68;
#pragma unroll
      for (int t = 0; t < 4; ++t) {
        float pv = __expf(s_acc[t][r]);
        l_lane[r] += pv;
        Ps[prow + t * 16 + col] = f2bf_rna(pv);
      }
    }

    // O += P . V
#pragma unroll
    for (int kk = 0; kk < 2; ++kk) {
      int pbase = (wave * 16 + col) * 68 + kk * 32 + quad * 8;
      short4v plo = *(const short4v*)&Ps[pbase];
      short4v phi = *(const short4v*)&Ps[pbase + 4];
      short8 ap = __builtin_shufflevector(plo, phi, 0, 1, 2, 3, 4, 5, 6, 7);
#pragma unroll
      for (int t = 0; t < 4; ++t) {
        short8 bv = *(const short8*)&Vs[buf][(t * 16 + col) * 64 + (((kk * 4 + quad) ^ (col & 7)) * 8)];
        o_acc[t] = __builtin_amdgcn_mfma_f32_16x16x32_bf16(ap, bv, o_acc[t], 0, 0, 0);
      }
    }

    if (kt < 15) {
      int nbuf = buf ^ 1;
      *(uint4*)&Ks[nbuf][krow0 * 64 + ((kblk0 ^ (krow0 & 7)) * 8)] = nk0;
      *(uint4*)&Ks[nbuf][krow1 * 64 + ((kblk1 ^ (krow1 & 7)) * 8)] = nk1;
      *(uint4*)&Vs[nbuf][vic * 64 + (((vseg * 2 + 0) ^ (vic & 7)) * 8)] = nv0;
      *(uint4*)&Vs[nbuf][vic * 64 + (((vseg * 2 + 1) ^ (vic & 7)) * 8)] = nv1;
      __syncthreads();
    }
  }

  // epilogue: reduce l across the quad group, normalize, store
#pragma unroll
  for (int r = 0; r < 4; ++r) {
    float l = l_lane[r];
    l += __shfl_xor(l, 1);
    l += __shfl_xor(l, 2);
    l += __shfl_xor(l, 4);
    l += __shfl_xor(l, 8);
    float inv = 1.0f / l;
    size_t row = ((size_t)(b * NPIX + qt * 64 + wave * 16 + quad * 4 + r)) * ICH;
#pragma unroll
    for (int t = 0; t < 4; ++t)
      attbuf[row + t * 16 + col] = f2bf(o_acc[t][r] * inv);
  }
}

// ---------------------------------------------------------------------------
// K3: out[b][o][p] = attended[p][:] . W[o][:] + W_b[o] + x[b][o][p], MFMA.
// Grid 1024 = 8 b x 128 pixel-tiles of 32. Wave: 64 o x 32 p. No LDS.
// W-frags from Wbf2 (coalesced layout).
// ---------------------------------------------------------------------------
__global__ __launch_bounds__(256, 4) void outconv_kernel(
    const ushort_t* __restrict__ attbuf, const float* __restrict__ x,
    const ushort_t* __restrict__ Wbf2, const float* __restrict__ W_b,
    float* __restrict__ out) {
  int tid = threadIdx.x;
  int wave = tid >> 6, lane = tid & 63;
  int quad = lane >> 4, col = lane & 15;
  int b = blockIdx.x >> 7, pt = blockIdx.x & 127;

  float4v acc[4][2];  // [os][ps]
#pragma unroll
  for (int os = 0; os < 4; ++os) {
    float bv = W_b[wave * 64 + os * 16 + col];
    float4v bvec = {bv, bv, bv, bv};
    acc[os][0] = bvec;
    acc[os][1] = bvec;
  }

  short8 af[2][2];  // [ks][ps]
#pragma unroll
  for (int ps = 0; ps < 2; ++ps)
#pragma unroll
    for (int ks = 0; ks < 2; ++ks)
      af[ks][ps] = *(const short8*)&attbuf[((size_t)(b * NPIX + pt * 32 + ps * 16 + col)) * ICH +
                                           ks * 32 + quad * 8];

  const uint4* W16 = (const uint4*)Wbf2;
#pragma unroll
  for (int os = 0; os < 4; ++os) {
#pragma unroll
    for (int ks = 0; ks < 2; ++ks) {
      uint4 wr = W16[(ks * 4 + quad) * 256 + wave * 64 + os * 16 + col];
      short8 wf = *(const short8*)&wr;
      acc[os][0] = __builtin_amdgcn_mfma_f32_16x16x32_bf16(af[ks][0], wf, acc[os][0], 0, 0, 0);
      acc[os][1] = __builtin_amdgcn_mfma_f32_16x16x32_bf16(af[ks][1], wf, acc[os][1], 0, 0, 0);
    }
  }

#pragma unroll
  for (int os = 0; os < 4; ++os) {
#pragma unroll
    for (int ps = 0; ps < 2; ++ps) {
      int o = wave * 64 + os * 16 + col;
      int p = pt * 32 + ps * 16 + quad * 4;
      size_t idx = ((size_t)(b * CC + o)) * NPIX + p;
      float4 xv = *(const float4*)&x[idx];
      float4 ov;
      ov.x = acc[os][ps][0] + xv.x;
      ov.y = acc[os][ps][1] + xv.y;
      ov.z = acc[os][ps][2] + xv.z;
      ov.w = acc[os][ps][3] + xv.w;
      *(float4*)&out[idx] = ov;
    }
  }
}

// ---------------------------------------------------------------------------
extern "C" void kernel_launch(void* const* d_in, const int* in_sizes, int n_in,
                              void* d_out, int out_size, void* d_ws, size_t ws_size,
                              hipStream_t stream) {
  const float* x       = (const float*)d_in[0];
  const float* g_w     = (const float*)d_in[1];
  const float* g_b     = (const float*)d_in[2];
  const float* theta_w = (const float*)d_in[3];
  const float* theta_b = (const float*)d_in[4];
  const float* phi_w   = (const float*)d_in[5];
  const float* phi_b   = (const float*)d_in[6];
  const float* W_w     = (const float*)d_in[7];
  const float* W_b     = (const float*)d_in[8];
  (void)in_sizes; (void)n_in; (void)out_size; (void)ws_size;

  char* ws = (char*)d_ws;
  ushort_t* wA2     = (ushort_t*)(ws + 0);         // 96KB bf16 [32][192][8]
  ushort_t* Wbf2    = (ushort_t*)(ws + 98304);     // 32KB bf16 [8][256][8]
  float*    biasAll = (float*)(ws + 131072);       // 768B
  ushort_t* xT      = (ushort_t*)(ws + 262144);    // 16.78MB bf16 [8][4096][256]
  ushort_t* attbuf  = (ushort_t*)(ws + 262144);    // alias xT (dead after qkv)
  ushort_t* qbuf    = (ushort_t*)(ws + 17039360);  // 4MB bf16 [8][4096][64]
  ushort_t* kTbuf   = (ushort_t*)(ws + 21233664);  // 1MB bf16 [8][1024][64]
  ushort_t* vTbuf   = (ushort_t*)(ws + 22282240);  // 1MB bf16 [8][64][1024]
  float* out = (float*)d_out;

  xpose_prep_kernel<<<2305, 256, 0, stream>>>(x, theta_w, phi_w, g_w, W_w,
                                              theta_b, phi_b, g_b,
                                              xT, wA2, Wbf2, biasAll);
  qkv_kernel<<<512, 256, 0, stream>>>(xT, wA2, biasAll, qbuf, kTbuf, vTbuf);
  attn_kernel<<<512, 256, 0, stream>>>(qbuf, kTbuf, vTbuf, attbuf);
  outconv_kernel<<<1024, 256, 0, stream>>>(attbuf, x, Wbf2, W_b, out);
}

// Round 6
// 132.227 us; speedup vs baseline: 1.5912x; 1.0514x over previous
//
#include <hip/hip_runtime.h>

typedef unsigned short ushort_t;
typedef unsigned int   uint_t;

typedef __attribute__((ext_vector_type(8))) short  short8;   // 8 bf16 in 4 VGPRs
typedef __attribute__((ext_vector_type(4))) short  short4v;  // 4 bf16 (b64)
typedef __attribute__((ext_vector_type(4))) float  float4v;  // MFMA 16x16 acc

#define BB    8
#define CC    256
#define HH    64
#define WW2   64
#define NPIX  4096   // H*W
#define MPOS  1024   // (H/2)*(W/2)
#define ICH   64

__device__ __forceinline__ float bf2f(ushort_t u) {
  return __uint_as_float(((uint_t)u) << 16);
}
__device__ __forceinline__ ushort_t f2bf(float f) {
  uint_t i = __float_as_uint(f);
  uint_t r = (i + 0x7FFFu + ((i >> 16) & 1u)) >> 16;  // RNE
  return (ushort_t)r;
}
__device__ __forceinline__ ushort_t f2bf_rna(float f) {   // cheap round-half-away
  return (ushort_t)((__float_as_uint(f) + 0x8000u) >> 16);
}
__device__ __forceinline__ uint_t pack2(float a, float b) {
  return (uint_t)f2bf(a) | ((uint_t)f2bf(b) << 16);
}

// ---------------------------------------------------------------------------
// K0: weight prep into coalesced-fragment layouts:
//   wA2 [32 kblk][192 o][8 k]  (A-op frags, 16 consecutive uint4 per quad)
//   Wbf2 [8 icblk][256 o][8 ic] (B-op frags for outconv)
//   biasAll [192] f32
// ---------------------------------------------------------------------------
__global__ __launch_bounds__(256) void prep_kernel(
    const float* __restrict__ theta_w, const float* __restrict__ phi_w,
    const float* __restrict__ g_w, const float* __restrict__ W_w,
    const float* __restrict__ theta_b, const float* __restrict__ phi_b,
    const float* __restrict__ g_b,
    ushort_t* __restrict__ wA2, ushort_t* __restrict__ Wbf2,
    float* __restrict__ biasAll) {
  int i = blockIdx.x * 256 + threadIdx.x;
  if (i < 49152) {         // theta|phi|g -> wA2
    float v = (i < 16384) ? theta_w[i]
            : (i < 32768) ? phi_w[i - 16384]
                          : g_w[i - 32768];
    int o = i >> 8, c = i & 255;
    wA2[(c >> 3) * 1536 + o * 8 + (c & 7)] = f2bf(v);
  } else if (i < 65536) {  // W_w -> Wbf2
    int j = i - 49152;
    int o = j >> 6, ic = j & 63;
    Wbf2[(ic >> 3) * 2048 + o * 8 + (ic & 7)] = f2bf(W_w[j]);
  } else if (i < 65600)    biasAll[i - 65536] = theta_b[i - 65536];
  else if (i < 65664)      biasAll[i - 65536] = phi_b[i - 65600];
  else if (i < 65728)      biasAll[i - 65536] = g_b[i - 65664];
}

// ---------------------------------------------------------------------------
// K1: q/k/v conv GEMM + 2x2 maxpool, reading x fp32 directly.
// Grid 512 = 8 b x 32 row-pairs x 2 col-halves; tile = 64 pixels
// (rows {2rj,2rj+1} x cols [32h,32h+32)), K=256 fully resident in LDS.
// Staging: wave = 64-channel group; lanes span the 64 pixels -> coalesced
// scalar fp32 loads; pack bf16 pairs; XOR-swizzled ds_write_b128. ONE barrier.
// Then M=192 x N=64 x K=256 MFMA (96/wave) + in-register pooling epilogue.
// ---------------------------------------------------------------------------
__global__ __launch_bounds__(256, 2) void qkv_kernel(
    const float* __restrict__ x, const ushort_t* __restrict__ wA2,
    const float* __restrict__ biasAll,
    ushort_t* __restrict__ qbuf, ushort_t* __restrict__ kTbuf,
    ushort_t* __restrict__ vTbuf) {
  __shared__ __align__(16) ushort_t Bsu[64 * 256];
  uint4* Bs16 = (uint4*)Bsu;
  int tid = threadIdx.x;
  int wave = tid >> 6, lane = tid & 63;
  int quad = lane >> 4, col = lane & 15;
  int b = blockIdx.x >> 6, t = blockIdx.x & 63;
  int rj = t >> 1, h = t & 1;

  // ---- stage x tile: thread covers pixel `pos`, channels [cg*64, cg*64+64)
  {
    int pos = tid & 63, cg = tid >> 6;
    int prow = pos >> 5, pcol = pos & 31;
    const float* xsrc = x + (size_t)b * (CC * NPIX) +
                        (size_t)(2 * rj + prow) * WW2 + h * 32 + pcol;
#pragma unroll
    for (int g = 0; g < 8; ++g) {
      float v[8];
#pragma unroll
      for (int j = 0; j < 8; ++j)
        v[j] = xsrc[(size_t)(cg * 64 + g * 8 + j) * NPIX];
      uint4 w;
      w.x = pack2(v[0], v[1]);
      w.y = pack2(v[2], v[3]);
      w.z = pack2(v[4], v[5]);
      w.w = pack2(v[6], v[7]);
      int jb = cg * 8 + g;  // 16B-block index in K (0..31)
      Bs16[pos * 32 + (jb & ~7) + ((jb & 7) ^ (pos & 7))] = w;
    }
  }
  __syncthreads();

  float4v acc[3][4];
#pragma unroll
  for (int ot = 0; ot < 3; ++ot) {
    int ob = wave * 48 + ot * 16 + quad * 4;
    float4v bv;
#pragma unroll
    for (int r = 0; r < 4; ++r) bv[r] = biasAll[ob + r];
#pragma unroll
    for (int s = 0; s < 4; ++s) acc[ot][s] = bv;
  }

  const uint4* wA16 = (const uint4*)wA2;
#pragma unroll
  for (int ks = 0; ks < 8; ++ks) {
    int kblk = ks * 4 + quad;               // 16B-block index in K (0..31)
    short8 aw[3];
#pragma unroll
    for (int ot = 0; ot < 3; ++ot) {
      uint4 a = wA16[kblk * 192 + wave * 48 + ot * 16 + col];
      aw[ot] = *(const short8*)&a;
    }
#pragma unroll
    for (int s = 0; s < 4; ++s) {
      int lp = s * 16 + col;
      uint4 braw = Bs16[lp * 32 + (kblk & ~7) + ((kblk & 7) ^ (lp & 7))];
      short8 bx = *(const short8*)&braw;
#pragma unroll
      for (int ot = 0; ot < 3; ++ot)
        acc[ot][s] = __builtin_amdgcn_mfma_f32_16x16x32_bf16(aw[ot], bx, acc[ot][s], 0, 0, 0);
    }
  }

  // epilogue: lane value (o = ob+quad*4+r, lp = s*16+col)
#pragma unroll
  for (int ot = 0; ot < 3; ++ot) {
    int ob = wave * 48 + ot * 16;
    if (ob < 64) {  // theta -> qbuf[b][n][o]
#pragma unroll
      for (int s = 0; s < 4; ++s) {
        int n = (2 * rj + (s >> 1)) * WW2 + h * 32 + (s & 1) * 16 + col;
        uint2 u;
        u.x = pack2(acc[ot][s][0], acc[ot][s][1]);
        u.y = pack2(acc[ot][s][2], acc[ot][s][3]);
        *(uint2*)&qbuf[((size_t)(b * NPIX + n)) * ICH + ob + quad * 4] = u;
      }
    } else if (ob < 128) {  // phi -> pool -> kTbuf[b][m][ic]
#pragma unroll
      for (int s = 0; s < 2; ++s) {
        float4v pm;
#pragma unroll
        for (int r = 0; r < 4; ++r) {
          float v = fmaxf(acc[ot][s][r], acc[ot][s + 2][r]);
          pm[r] = fmaxf(v, __shfl_xor(v, 1));
        }
        if ((lane & 1) == 0) {
          int m = rj * 32 + h * 16 + s * 8 + (col >> 1);
          uint2 u;
          u.x = pack2(pm[0], pm[1]);
          u.y = pack2(pm[2], pm[3]);
          *(uint2*)&kTbuf[((size_t)(b * MPOS + m)) * ICH + (ob - 64) + quad * 4] = u;
        }
      }
    } else {  // g -> pool -> vTbuf[b][ic][m]
#pragma unroll
      for (int s = 0; s < 2; ++s) {
        float4v pm;
#pragma unroll
        for (int r = 0; r < 4; ++r) {
          float v = fmaxf(acc[ot][s][r], acc[ot][s + 2][r]);
          pm[r] = fmaxf(v, __shfl_xor(v, 1));
        }
        if ((lane & 1) == 0) {
          int m = rj * 32 + h * 16 + s * 8 + (col >> 1);
#pragma unroll
          for (int r = 0; r < 4; ++r)
            vTbuf[((size_t)(b * ICH + (ob - 128) + quad * 4 + r)) * MPOS + m] = f2bf(pm[r]);
        }
      }
    }
  }
}

// ---------------------------------------------------------------------------
// K2: FUSED attention + output conv + residual.
// Attention part = r5 structure (no-max softmax, XOR-swizzled K/V dbuf,
// one barrier/kt). Ps stride 72 -> 16B-aligned b128 A-frags.
// Then: normalize O into wave-private Ps rows (bf16, no barrier needed),
// outconv D[m=p][n=o] with A = attended rows (LDS), B = Wbf2 (L2-hot),
// fused float4 residual add + store of out.
// ---------------------------------------------------------------------------
__global__ __launch_bounds__(256, 2) void attn_out_kernel(
    const ushort_t* __restrict__ qbuf, const ushort_t* __restrict__ kTbuf,
    const ushort_t* __restrict__ vTbuf, const ushort_t* __restrict__ Wbf2,
    const float* __restrict__ W_b, const float* __restrict__ x,
    float* __restrict__ out) {
  __shared__ __align__(16) ushort_t Ks[2][64 * 64];
  __shared__ __align__(16) ushort_t Vs[2][64 * 64];
  __shared__ __align__(16) ushort_t Ps[64 * 72];
  int tid  = threadIdx.x;
  int wave = tid >> 6, lane = tid & 63;
  int quad = lane >> 4, col = lane & 15;
  int b = blockIdx.x >> 6, qt = blockIdx.x & 63;

  // Q A-fragments straight from global (one-time)
  const ushort_t* qrow = qbuf + ((size_t)(b * NPIX + qt * 64 + wave * 16 + col)) * ICH;
  short8 aQ0 = *(const short8*)&qrow[quad * 8];
  short8 aQ1 = *(const short8*)&qrow[32 + quad * 8];

  int krow0 = tid >> 3,           kblk0 = tid & 7;
  int krow1 = (tid + 256) >> 3,   kblk1 = tid & 7;
  int vic = tid >> 2, vseg = tid & 3;

  const uint4* ksrc0 = (const uint4*)(kTbuf + ((size_t)(b * MPOS)) * ICH);
  const ushort_t* vbase = vTbuf + ((size_t)(b * ICH + vic)) * MPOS;

  {
    uint4 k0 = ksrc0[tid], k1 = ksrc0[tid + 256];
    const uint4* vsrc = (const uint4*)(vbase + vseg * 16);
    uint4 v0 = vsrc[0], v1 = vsrc[1];
    *(uint4*)&Ks[0][krow0 * 64 + ((kblk0 ^ (krow0 & 7)) * 8)] = k0;
    *(uint4*)&Ks[0][krow1 * 64 + ((kblk1 ^ (krow1 & 7)) * 8)] = k1;
    *(uint4*)&Vs[0][vic * 64 + (((vseg * 2 + 0) ^ (vic & 7)) * 8)] = v0;
    *(uint4*)&Vs[0][vic * 64 + (((vseg * 2 + 1) ^ (vic & 7)) * 8)] = v1;
  }
  __syncthreads();

  const float4v zero4 = {0.f, 0.f, 0.f, 0.f};
  float l_lane[4] = {0.f, 0.f, 0.f, 0.f};
  float4v o_acc[4];
#pragma unroll
  for (int t = 0; t < 4; ++t) o_acc[t] = zero4;

  for (int kt = 0; kt < 16; ++kt) {
    uint4 nk0, nk1, nv0, nv1;
    if (kt < 15) {
      const uint4* ksrc = (const uint4*)(kTbuf + ((size_t)(b * MPOS + (kt + 1) * 64)) * ICH);
      nk0 = ksrc[tid];
      nk1 = ksrc[tid + 256];
      const uint4* vsrc = (const uint4*)(vbase + (kt + 1) * 64 + vseg * 16);
      nv0 = vsrc[0];
      nv1 = vsrc[1];
    }
    int buf = kt & 1;

    // S = Q . K^T
    float4v s_acc[4];
#pragma unroll
    for (int t = 0; t < 4; ++t) {
      float4v s = zero4;
      short8 bk0 = *(const short8*)&Ks[buf][(t * 16 + col) * 64 + ((quad ^ (col & 7)) * 8)];
      s = __builtin_amdgcn_mfma_f32_16x16x32_bf16(aQ0, bk0, s, 0, 0, 0);
      short8 bk1 = *(const short8*)&Ks[buf][(t * 16 + col) * 64 + (((4 + quad) ^ (col & 7)) * 8)];
      s = __builtin_amdgcn_mfma_f32_16x16x32_bf16(aQ1, bk1, s, 0, 0, 0);
      s_acc[t] = s;
    }

    // P = exp(S); per-lane l accumulation; wave-private Ps rows
#pragma unroll
    for (int r = 0; r < 4; ++r) {
      int prow = (wave * 16 + quad * 4 + r) * 72;
#pragma unroll
      for (int t = 0; t < 4; ++t) {
        float pv = __expf(s_acc[t][r]);
        l_lane[r] += pv;
        Ps[prow + t * 16 + col] = f2bf_rna(pv);
      }
    }

    // O += P . V
#pragma unroll
    for (int kk = 0; kk < 2; ++kk) {
      short8 ap = *(const short8*)&Ps[(wave * 16 + col) * 72 + kk * 32 + quad * 8];
#pragma unroll
      for (int t = 0; t < 4; ++t) {
        short8 bv = *(const short8*)&Vs[buf][(t * 16 + col) * 64 + (((kk * 4 + quad) ^ (col & 7)) * 8)];
        o_acc[t] = __builtin_amdgcn_mfma_f32_16x16x32_bf16(ap, bv, o_acc[t], 0, 0, 0);
      }
    }

    if (kt < 15) {
      int nbuf = buf ^ 1;
      *(uint4*)&Ks[nbuf][krow0 * 64 + ((kblk0 ^ (krow0 & 7)) * 8)] = nk0;
      *(uint4*)&Ks[nbuf][krow1 * 64 + ((kblk1 ^ (krow1 & 7)) * 8)] = nk1;
      *(uint4*)&Vs[nbuf][vic * 64 + (((vseg * 2 + 0) ^ (vic & 7)) * 8)] = nv0;
      *(uint4*)&Vs[nbuf][vic * 64 + (((vseg * 2 + 1) ^ (vic & 7)) * 8)] = nv1;
      __syncthreads();
    }
  }

  // normalize O, write attended rows (bf16) into wave-private Ps rows.
  // No barrier: each wave only reads back its own rows (same-wave DS order).
#pragma unroll
  for (int r = 0; r < 4; ++r) {
    float l = l_lane[r];
    l += __shfl_xor(l, 1);
    l += __shfl_xor(l, 2);
    l += __shfl_xor(l, 4);
    l += __shfl_xor(l, 8);
    float inv = 1.0f / l;
    int prow = (wave * 16 + quad * 4 + r) * 72;
#pragma unroll
    for (int t = 0; t < 4; ++t)
      Ps[prow + t * 16 + col] = f2bf(o_acc[t][r] * inv);
  }

  // ---- fused output conv: D[m=p(16 per wave)][n=o(256)] + residual ----
  float4v cacc[16];
#pragma unroll
  for (int ot = 0; ot < 16; ++ot) {
    float bv = W_b[ot * 16 + col];
    float4v bvec = {bv, bv, bv, bv};
    cacc[ot] = bvec;
  }
  const uint4* W16 = (const uint4*)Wbf2;
#pragma unroll
  for (int ks = 0; ks < 2; ++ks) {
    short8 ap = *(const short8*)&Ps[(wave * 16 + col) * 72 + ks * 32 + quad * 8];
#pragma unroll
    for (int ot = 0; ot < 16; ++ot) {
      uint4 wr = W16[(ks * 4 + quad) * 256 + ot * 16 + col];
      short8 wf = *(const short8*)&wr;
      cacc[ot] = __builtin_amdgcn_mfma_f32_16x16x32_bf16(ap, wf, cacc[ot], 0, 0, 0);
    }
  }

  int pbase = qt * 64 + wave * 16 + quad * 4;
#pragma unroll
  for (int ot = 0; ot < 16; ++ot) {
    int o = ot * 16 + col;
    size_t idx = ((size_t)(b * CC + o)) * NPIX + pbase;
    float4 xv = *(const float4*)&x[idx];
    float4 ov;
    ov.x = cacc[ot][0] + xv.x;
    ov.y = cacc[ot][1] + xv.y;
    ov.z = cacc[ot][2] + xv.z;
    ov.w = cacc[ot][3] + xv.w;
    *(float4*)&out[idx] = ov;
  }
}

// ---------------------------------------------------------------------------
extern "C" void kernel_launch(void* const* d_in, const int* in_sizes, int n_in,
                              void* d_out, int out_size, void* d_ws, size_t ws_size,
                              hipStream_t stream) {
  const float* x       = (const float*)d_in[0];
  const float* g_w     = (const float*)d_in[1];
  const float* g_b     = (const float*)d_in[2];
  const float* theta_w = (const float*)d_in[3];
  const float* theta_b = (const float*)d_in[4];
  const float* phi_w   = (const float*)d_in[5];
  const float* phi_b   = (const float*)d_in[6];
  const float* W_w     = (const float*)d_in[7];
  const float* W_b     = (const float*)d_in[8];
  (void)in_sizes; (void)n_in; (void)out_size; (void)ws_size;

  char* ws = (char*)d_ws;
  ushort_t* wA2     = (ushort_t*)(ws + 0);         // 96KB bf16 [32][192][8]
  ushort_t* Wbf2    = (ushort_t*)(ws + 98304);     // 32KB bf16 [8][256][8]
  float*    biasAll = (float*)(ws + 131072);       // 768B
  ushort_t* qbuf    = (ushort_t*)(ws + 262144);    // 4MB bf16 [8][4096][64]
  ushort_t* kTbuf   = (ushort_t*)(ws + 4456448);   // 1MB bf16 [8][1024][64]
  ushort_t* vTbuf   = (ushort_t*)(ws + 5505024);   // 1MB bf16 [8][64][1024]
  float* out = (float*)d_out;

  prep_kernel<<<257, 256, 0, stream>>>(theta_w, phi_w, g_w, W_w,
                                       theta_b, phi_b, g_b,
                                       wA2, Wbf2, biasAll);
  qkv_kernel<<<512, 256, 0, stream>>>(x, wA2, biasAll, qbuf, kTbuf, vTbuf);
  attn_out_kernel<<<512, 256, 0, stream>>>(qbuf, kTbuf, vTbuf, Wbf2, W_b, x, out);
}